// Round 1
// baseline (116.419 us; speedup 1.0000x reference)
//
#include <hip/hip_runtime.h>

#define NQ 10
#define TS 10
#define DIM 1024
#define ND 1024
#define RPT 16   // DIM / 64 amplitudes per lane

// One wave (64 lanes) per sample. Lane L holds amplitudes idx = r*64 + L,
// r = 0..15. Qubit i acts on idx bit (9-i): bits 6..9 are the r-index
// (in-thread pairs), bits 0..5 are lane bits (__shfl_xor pairs).
// No LDS, no barriers.
__global__ __launch_bounds__(64) void qsim_kernel(
    const float* __restrict__ re_in, const float* __restrict__ im_in,
    const float* __restrict__ phis, const float* __restrict__ gs,
    float* __restrict__ out)
{
    const int sample = blockIdx.x;
    const int lane = threadIdx.x;

    const float* pr_in = re_in + sample * DIM;
    const float* pi_in = im_in + sample * DIM;

    float pr[RPT], pim[RPT];
#pragma unroll
    for (int r = 0; r < RPT; ++r) {
        pr[r]  = pr_in[r * 64 + lane];
        pim[r] = pi_in[r * 64 + lane];
    }

    // ---- normalize: norm over the sample's 1024 amplitudes ----
    float nrm = 0.f;
#pragma unroll
    for (int r = 0; r < RPT; ++r) nrm += pr[r] * pr[r] + pim[r] * pim[r];
#pragma unroll
    for (int off = 32; off >= 1; off >>= 1) nrm += __shfl_xor(nrm, off, 64);
    const float scl = rsqrtf(nrm);
#pragma unroll
    for (int r = 0; r < RPT; ++r) { pr[r] *= scl; pim[r] *= scl; }

    // ---- pairsum per amplitude: 0.5*((10-2*popc(idx))^2 - 10) ----
    float ps[RPT];
#pragma unroll
    for (int r = 0; r < RPT; ++r) {
        const int idx = r * 64 + lane;
        const int zs = NQ - 2 * __popc(idx);
        ps[r] = 0.5f * (float)(zs * zs - NQ);
    }

    const float* ph = phis + sample * (3 * NQ * TS);
    const float inv = 0.15811388300841897f;  // 1/(2*sqrt(10))

    for (int tt = 0; tt < TS; ++tt) {
        const int base = 3 * NQ * tt;
#pragma unroll
        for (int i = 0; i < NQ; ++i) {
            const float a  = ph[base + i];
            const float th = ph[base + NQ + i];
            const float b  = ph[base + 2 * NQ + i];
            float c, s, cp, sp, cm, sm;
            __sincosf(0.5f * th,      &s,  &c);
            __sincosf(0.5f * (a + b), &sp, &cp);
            __sincosf(0.5f * (a - b), &sm, &cm);
            // M00=(A,-B)  M01=(-C,-D)  M10=(C,-D)  M11=(A,B)
            const float A = c * cp, B = c * sp, C = s * cm, D = s * sm;

            const int bitpos = NQ - 1 - i;  // 9-i
            if (bitpos >= 6) {
                // in-thread pairing on r-bit (bitpos-6)
                const int rb = bitpos - 6;
#pragma unroll
                for (int r0 = 0; r0 < RPT; ++r0) {
                    if ((r0 >> rb) & 1) continue;
                    const int r1 = r0 | (1 << rb);
                    const float x0r = pr[r0], x0i = pim[r0];
                    const float x1r = pr[r1], x1i = pim[r1];
                    pr[r0]  = A * x0r + B * x0i - C * x1r + D * x1i;
                    pim[r0] = A * x0i - B * x0r - C * x1i - D * x1r;
                    pr[r1]  = C * x0r + D * x0i + A * x1r - B * x1i;
                    pim[r1] = C * x0i - D * x0r + A * x1i + B * x1r;
                }
            } else {
                // cross-lane pairing via shfl_xor
                const int mask = 1 << bitpos;
                const bool hi = (lane & mask) != 0;
                const float sgn = hi ? 1.f : -1.f;
                const float ownI  = sgn * B;  // own coeff  = (A, ownI)
                const float partR = sgn * C;  // part coeff = (partR, -D)
#pragma unroll
                for (int r = 0; r < RPT; ++r) {
                    const float qr = __shfl_xor(pr[r],  mask, 64);
                    const float qi = __shfl_xor(pim[r], mask, 64);
                    const float orr = pr[r], oi = pim[r];
                    pr[r]  = A * orr - ownI * oi + partR * qr + D * qi;
                    pim[r] = A * oi  + ownI * orr + partR * qi - D * qr;
                }
            }
        }
        // ---- diagonal phase: psi *= exp(-0.5i * theta * pairsum) ----
        const float theta = gs[sample * TS + tt] * inv;
        const float k = -0.5f * theta;
#pragma unroll
        for (int r = 0; r < RPT; ++r) {
            float sa, ca;
            __sincosf(k * ps[r], &sa, &ca);
            const float xr = pr[r], xi = pim[r];
            pr[r]  = xr * ca - xi * sa;
            pim[r] = xr * sa + xi * ca;
        }
    }

#pragma unroll
    for (int r = 0; r < RPT; ++r) {
        out[sample * DIM + r * 64 + lane]            = pr[r];
        out[ND * DIM + sample * DIM + r * 64 + lane] = pim[r];
    }
}

extern "C" void kernel_launch(void* const* d_in, const int* in_sizes, int n_in,
                              void* d_out, int out_size, void* d_ws, size_t ws_size,
                              hipStream_t stream) {
    const float* re_in = (const float*)d_in[0];
    const float* im_in = (const float*)d_in[1];
    const float* phis  = (const float*)d_in[2];
    const float* gs    = (const float*)d_in[3];
    float* out = (float*)d_out;
    qsim_kernel<<<ND, 64, 0, stream>>>(re_in, im_in, phis, gs, out);
}